// Round 5
// baseline (503.084 us; speedup 1.0000x reference)
//
#include <hip/hip_runtime.h>

// B=2, T=2048, C=1024, H=16, HD=64. Inputs f32, OUTPUT F32 (reference returns f32;
// rounds 1-4 failed identically because we wrote bf16 into an f32-read buffer).
// Pipeline: convert->bf16, QKV GEMM (MFMA), RoPE+split (+V transpose),
// flash attention (swapped-QK^T MFMA, softmax in-register), proj GEMM -> f32 out.
// ws plan (48 MiB):
//   [0,24M)  qkv   -> dead after rope; [0,8M) attn out, [8,10M) W_proj bf16
//   [24,32M) xb    -> dead after gemm1; reused as Q (B,H,T,64)
//   [32,38M) wqkvb -> dead after gemm1; reused as K (B,H,T,64) [32,40M)
//   [40,48M) V^T   (B,H,64,T)

typedef short  bf16x8 __attribute__((ext_vector_type(8)));
typedef float  f32x4  __attribute__((ext_vector_type(4)));
typedef unsigned short u16x4 __attribute__((ext_vector_type(4)));
typedef unsigned short u16x2 __attribute__((ext_vector_type(2)));

#define B_  2
#define T_  2048
#define C_  1024
#define H_  16
#define HD_ 64

static __device__ __forceinline__ unsigned short f2bf(float f) {
    union { float f; unsigned u; } v; v.f = f;
    unsigned r = v.u + 0x7fffu + ((v.u >> 16) & 1u);   // RNE
    return (unsigned short)(r >> 16);
}
static __device__ __forceinline__ float bf2f(unsigned short s) {
    union { unsigned u; float f; } v; v.u = ((unsigned)s) << 16;
    return v.f;
}

// ---------------- f32 -> bf16 convert (vector x4) ----------------
__global__ void convert_f32_bf16(const float* __restrict__ in,
                                 unsigned short* __restrict__ out, int n4) {
    int i = blockIdx.x * blockDim.x + threadIdx.x;
    if (i >= n4) return;
    float4 f = ((const float4*)in)[i];
    u16x4 o; o[0] = f2bf(f.x); o[1] = f2bf(f.y); o[2] = f2bf(f.z); o[3] = f2bf(f.w);
    ((u16x4*)out)[i] = o;
}

// ---------------- GEMM: C[m][n] = sum_k A[m][k]*B[n][k] (+bias) ----------------
// A: MxK bf16 row-major, B: NxK bf16 row-major, C: MxN (bf16 or f32).
// 4 waves/block (2x2), 64x64 per wave, pure register tiling.
__global__ __launch_bounds__(256) void gemm_nt(const unsigned short* __restrict__ A,
                                               const unsigned short* __restrict__ Bm,
                                               void* __restrict__ Cm,
                                               const float* __restrict__ bias,
                                               int M, int N, int K, int out_f32) {
    const int w    = threadIdx.x >> 6;
    const int lane = threadIdx.x & 63;
    const int r    = lane & 15, g = lane >> 4;
    const int m0   = blockIdx.y * 128 + (w >> 1) * 64;
    const int n0   = blockIdx.x * 128 + (w & 1) * 64;

    f32x4 acc[4][4];
    for (int i = 0; i < 4; i++)
        for (int j = 0; j < 4; j++) acc[i][j] = (f32x4){0.f, 0.f, 0.f, 0.f};

    const unsigned short* Ap = A  + (size_t)(m0 + r) * K + 8 * g;
    const unsigned short* Bp = Bm + (size_t)(n0 + r) * K + 8 * g;

    for (int k0 = 0; k0 < K; k0 += 32) {
        bf16x8 a[4], b[4];
#pragma unroll
        for (int mi = 0; mi < 4; mi++) a[mi] = *(const bf16x8*)(Ap + (size_t)mi * 16 * K + k0);
#pragma unroll
        for (int ni = 0; ni < 4; ni++) b[ni] = *(const bf16x8*)(Bp + (size_t)ni * 16 * K + k0);
#pragma unroll
        for (int mi = 0; mi < 4; mi++)
#pragma unroll
            for (int ni = 0; ni < 4; ni++)
                acc[mi][ni] = __builtin_amdgcn_mfma_f32_16x16x32_bf16(a[mi], b[ni], acc[mi][ni], 0, 0, 0);
    }

    // C/D layout: col = lane&15, row = 4*(lane>>4) + reg
#pragma unroll
    for (int mi = 0; mi < 4; mi++) {
        int row = m0 + mi * 16 + 4 * g;
#pragma unroll
        for (int ni = 0; ni < 4; ni++) {
            int col = n0 + ni * 16 + r;
            float bv = bias ? bias[col] : 0.f;
#pragma unroll
            for (int j = 0; j < 4; j++) {
                float v = acc[mi][ni][j] + bv;
                size_t idx = (size_t)(row + j) * N + col;
                if (out_f32) ((float*)Cm)[idx] = v;
                else         ((unsigned short*)Cm)[idx] = f2bf(v);
            }
        }
    }
}

// ---------------- RoPE + split qkv -> Q,K (B,H,T,HD) and V^T (B,H,HD,T) ----------------
// fa/fb: cos and sin tables in unknown order; cos identified by fa[0]==1 (angle 0).
__global__ void rope_split(const unsigned short* __restrict__ qkv,
                           const float* __restrict__ fa, const float* __restrict__ fb,
                           unsigned short* __restrict__ Qo, unsigned short* __restrict__ Ko,
                           unsigned short* __restrict__ Vt) {
    const float* fcos = (fa[0] > 0.5f) ? fa : fb;
    const float* fsin = (fa[0] > 0.5f) ? fb : fa;
    int tid = blockIdx.x * blockDim.x + threadIdx.x;       // total = 4096*1536
    int m  = tid / 1536;
    int d2 = tid - m * 1536;
    int n  = d2 * 2;
    int b  = m >> 11, t = m & 2047;
    u16x2 in = *(const u16x2*)(qkv + (size_t)m * 3072 + n);
    if (n < 2048) {                                        // q or k: apply RoPE
        int nn = n & 1023;
        int h = nn >> 6, d = nn & 63;
        int i = d >> 1;
        float c = fcos[t * 32 + i], s = fsin[t * 32 + i];
        float re = bf2f(in[0]), im = bf2f(in[1]);
        u16x2 o; o[0] = f2bf(re * c - im * s); o[1] = f2bf(re * s + im * c);
        unsigned short* dst = (n < 1024) ? Qo : Ko;
        *(u16x2*)(dst + ((size_t)((b * 16 + h) * 2048 + t)) * 64 + d) = o;
    } else {                                               // v: transpose to (bh, d, t)
        int nn = n - 2048;
        int h = nn >> 6, d = nn & 63;
        size_t base = ((size_t)((b * 16 + h) * 64 + d)) * 2048 + t;
        Vt[base]        = in[0];
        Vt[base + 2048] = in[1];
    }
}

// ---------------- flash attention ----------------
// 1 wave per 16 q-rows. Swapped QK^T: S^T = mfma(A=K, B=Q) -> lane holds scores
// for q-row (lane&15) at keys 4g+j / 16+4g+j of each 32-key tile. P-regs feed
// O^T = mfma(A=V^T, B=P^T) directly (slot-consistent k mapping). Softmax stats
// per q-row reduce over the 4 lane groups via shfl_xor 16/32.
__global__ __launch_bounds__(256) void attn_fwd(const unsigned short* __restrict__ Q,
                                                const unsigned short* __restrict__ Kk,
                                                const unsigned short* __restrict__ Vt,
                                                unsigned short* __restrict__ O) {
    const int w    = threadIdx.x >> 6;
    const int lane = threadIdx.x & 63;
    const int l15  = lane & 15, g = lane >> 4;
    const int gw   = blockIdx.x * 4 + w;
    const int qb   = gw & 127;       // q-block within (b,h): 128 blocks of 16 rows
    const int bh   = gw >> 7;        // 0..31
    const int b    = bh >> 4, h = bh & 15;

    const unsigned short* Qb = Q  + (size_t)bh * T_ * HD_;
    const unsigned short* Kb = Kk + (size_t)bh * T_ * HD_;
    const unsigned short* Vb = Vt + (size_t)bh * HD_ * T_;

    const int qrow = qb * 16 + l15;
    bf16x8 qf0 = *(const bf16x8*)(Qb + (size_t)qrow * 64 + 8 * g);
    bf16x8 qf1 = *(const bf16x8*)(Qb + (size_t)qrow * 64 + 32 + 8 * g);

    f32x4 o[4];
#pragma unroll
    for (int ch = 0; ch < 4; ch++) o[ch] = (f32x4){0.f, 0.f, 0.f, 0.f};
    float m2 = -__builtin_inff(), lsum = 0.f;
    const float SCL = 0.125f * 1.4426950408889634f;  // HD^-0.5 * log2(e)

    const int ktmax = (qb * 16 + 15) >> 5;
    for (int kt = 0; kt <= ktmax; ++kt) {
        const int key0 = kt * 32;
        const unsigned short* kp = Kb + (size_t)(key0 + l15) * 64 + 8 * g;
        f32x4 s0 = (f32x4){0.f, 0.f, 0.f, 0.f};
        f32x4 s1 = (f32x4){0.f, 0.f, 0.f, 0.f};
        bf16x8 kf;
        kf = *(const bf16x8*)(kp);                 s0 = __builtin_amdgcn_mfma_f32_16x16x32_bf16(kf, qf0, s0, 0, 0, 0);
        kf = *(const bf16x8*)(kp + 32);            s0 = __builtin_amdgcn_mfma_f32_16x16x32_bf16(kf, qf1, s0, 0, 0, 0);
        kf = *(const bf16x8*)(kp + 16 * 64);       s1 = __builtin_amdgcn_mfma_f32_16x16x32_bf16(kf, qf0, s1, 0, 0, 0);
        kf = *(const bf16x8*)(kp + 16 * 64 + 32);  s1 = __builtin_amdgcn_mfma_f32_16x16x32_bf16(kf, qf1, s1, 0, 0, 0);

        float u0[4], u1[4];
        float tm = -__builtin_inff();
#pragma unroll
        for (int j = 0; j < 4; j++) {
            int k0j = key0 + 4 * g + j;
            u0[j] = (k0j <= qrow) ? s0[j] * SCL : -__builtin_inff();
            u1[j] = (k0j + 16 <= qrow) ? s1[j] * SCL : -__builtin_inff();
            tm = fmaxf(tm, fmaxf(u0[j], u1[j]));
        }
        tm = fmaxf(tm, __shfl_xor(tm, 16));
        tm = fmaxf(tm, __shfl_xor(tm, 32));
        float mnew  = fmaxf(m2, tm);
        float alpha = exp2f(m2 - mnew);
        float ps = 0.f;
        bf16x8 pf;
#pragma unroll
        for (int j = 0; j < 4; j++) {
            float p0 = exp2f(u0[j] - mnew);
            float p1 = exp2f(u1[j] - mnew);
            ps += p0 + p1;
            pf[j]     = (short)f2bf(p0);
            pf[4 + j] = (short)f2bf(p1);
        }
        lsum = lsum * alpha + ps;
        m2 = mnew;

#pragma unroll
        for (int ch = 0; ch < 4; ch++) {
            o[ch] *= alpha;
            const unsigned short* vp = Vb + (size_t)(16 * ch + l15) * 2048 + key0 + 4 * g;
            u16x4 vlo = *(const u16x4*)(vp);
            u16x4 vhi = *(const u16x4*)(vp + 16);
            bf16x8 va;
            va[0] = (short)vlo[0]; va[1] = (short)vlo[1]; va[2] = (short)vlo[2]; va[3] = (short)vlo[3];
            va[4] = (short)vhi[0]; va[5] = (short)vhi[1]; va[6] = (short)vhi[2]; va[7] = (short)vhi[3];
            o[ch] = __builtin_amdgcn_mfma_f32_16x16x32_bf16(va, pf, o[ch], 0, 0, 0);
        }
    }

    lsum += __shfl_xor(lsum, 16);
    lsum += __shfl_xor(lsum, 32);
    float inv = 1.f / lsum;

    // O layout (B,T,H,HD); lane writes q=l15 row, d = 16*ch + 4*g + j
    size_t obase = (((size_t)b * T_ + qb * 16 + l15) * H_ + h) * HD_;
#pragma unroll
    for (int ch = 0; ch < 4; ch++) {
        int d0 = 16 * ch + 4 * g;
        u16x4 ov;
#pragma unroll
        for (int j = 0; j < 4; j++) ov[j] = f2bf(o[ch][j] * inv);
        *(u16x4*)(O + obase + d0) = ov;
    }
}

extern "C" void kernel_launch(void* const* d_in, const int* in_sizes, int n_in,
                              void* d_out, int out_size, void* d_ws, size_t ws_size,
                              hipStream_t stream) {
    (void)out_size;
    // Input mapping by element count (order-independent); cos/sin disambiguated on device.
    const float *x = nullptr, *wqkv = nullptr, *wproj = nullptr, *bproj = nullptr;
    const float *fa = nullptr, *fb = nullptr;
    for (int i = 0; i < n_in; i++) {
        switch (in_sizes[i]) {
            case 4194304: x     = (const float*)d_in[i]; break;
            case 3145728: wqkv  = (const float*)d_in[i]; break;
            case 1048576: wproj = (const float*)d_in[i]; break;
            case 1024:    bproj = (const float*)d_in[i]; break;
            case 65536:   if (!fa) fa = (const float*)d_in[i]; else fb = (const float*)d_in[i]; break;
            default: break;
        }
    }
    if (!x || !wqkv || !wproj || !bproj || !fa || !fb) return;  // zero-output signature
    if (ws_size < (size_t)48 * 1024 * 1024) return;             // zero-output signature

    char* ws = (char*)d_ws;
    const size_t MB = 1024 * 1024;
    unsigned short* qkv    = (unsigned short*)(ws);            // [0,24M)
    unsigned short* oat    = (unsigned short*)(ws);            // [0,8M)   (after rope)
    unsigned short* wprojb = (unsigned short*)(ws + 8  * MB);  // [8,10M)  (after rope)
    unsigned short* xb     = (unsigned short*)(ws + 24 * MB);  // [24,32M)
    unsigned short* wqkvb  = (unsigned short*)(ws + 32 * MB);  // [32,38M)
    unsigned short* qro    = (unsigned short*)(ws + 24 * MB);  // [24,32M)
    unsigned short* kro    = (unsigned short*)(ws + 32 * MB);  // [32,40M)
    unsigned short* vt     = (unsigned short*)(ws + 40 * MB);  // [40,48M)

    convert_f32_bf16<<<4096, 256, 0, stream>>>(x,    xb,    4194304 / 4);
    convert_f32_bf16<<<3072, 256, 0, stream>>>(wqkv, wqkvb, 3145728 / 4);

    gemm_nt<<<dim3(3072 / 128, 4096 / 128), 256, 0, stream>>>(xb, wqkvb, qkv, nullptr,
                                                              4096, 3072, 1024, 0);

    rope_split<<<(4096 * 1536) / 256, 256, 0, stream>>>(qkv, fa, fb, qro, kro, vt);

    convert_f32_bf16<<<1024, 256, 0, stream>>>(wproj, wprojb, 1048576 / 4);

    attn_fwd<<<1024, 256, 0, stream>>>(qro, kro, vt, oat);

    // Final projection: f32 output (the reference's output dtype).
    gemm_nt<<<dim3(1024 / 128, 4096 / 128), 256, 0, stream>>>(oat, wprojb, d_out, bproj,
                                                              4096, 1024, 1024, 1);
}

// Round 6
// 277.715 us; speedup vs baseline: 1.8115x; 1.8115x over previous
//
#include <hip/hip_runtime.h>

// B=2, T=2048, C=1024, H=16, HD=64. Inputs f32, output f32.
// convert->bf16, QKV GEMM (MFMA + global_load_lds staging, m97 structure),
// RoPE+split (+V transpose), paired-causal flash attention (2 q-blocks/wave,
// KVBLK=64, shared K/V loads, cvt_pk softmax), proj GEMM -> f32.
// ws plan (48 MiB):
//   [0,24M)  qkv   -> dead after rope; [0,8M) attn out, [8,10M) W_proj bf16
//   [24,32M) xb    -> dead after gemm1; reused as Q (B,H,T,64)
//   [32,38M) wqkvb -> dead after gemm1; reused as K (B,H,T,64) [32,40M)
//   [40,48M) V^T   (B,H,64,T)

typedef short  bf16x8 __attribute__((ext_vector_type(8)));
typedef float  f32x4  __attribute__((ext_vector_type(4)));
typedef unsigned short u16x4 __attribute__((ext_vector_type(4)));
typedef unsigned short u16x2 __attribute__((ext_vector_type(2)));

#define B_  2
#define T_  2048
#define H_  16
#define HD_ 64
#define NINF (-__builtin_inff())

static __device__ __forceinline__ unsigned short f2bf(float f) {
    union { float f; unsigned u; } v; v.f = f;
    unsigned r = v.u + 0x7fffu + ((v.u >> 16) & 1u);   // RNE
    return (unsigned short)(r >> 16);
}
static __device__ __forceinline__ float bf2f(unsigned short s) {
    union { unsigned u; float f; } v; v.u = ((unsigned)s) << 16;
    return v.f;
}

#define GLOAD_LDS16(gp, lp)                                                              \
    __builtin_amdgcn_global_load_lds((const __attribute__((address_space(1))) void*)(gp), \
                                     (__attribute__((address_space(3))) void*)(lp), 16, 0, 0)

// ---------------- f32 -> bf16 convert (vector x4) ----------------
__global__ void convert_f32_bf16(const float* __restrict__ in,
                                 unsigned short* __restrict__ out, int n4) {
    int i = blockIdx.x * blockDim.x + threadIdx.x;
    if (i >= n4) return;
    float4 f = ((const float4*)in)[i];
    u16x4 o; o[0] = f2bf(f.x); o[1] = f2bf(f.y); o[2] = f2bf(f.z); o[3] = f2bf(f.w);
    ((u16x4*)out)[i] = o;
}

// ---------------- GEMM (m97 structure): C[m][n] = sum_k A[m][k]*B[n][k] (+bias) ---
// 128x128 tile, BK=32, 4 waves (2x2), LDS staging via global_load_lds width 16.
__global__ __launch_bounds__(256) void gemm_nt(const unsigned short* __restrict__ A,
                                               const unsigned short* __restrict__ Bm,
                                               void* __restrict__ Cm,
                                               const float* __restrict__ bias,
                                               int M, int N, int K, int out_f32) {
    __shared__ __align__(16) unsigned short As[128 * 32];
    __shared__ __align__(16) unsigned short Bs[128 * 32];
    const int tid  = threadIdx.x;
    const int w    = tid >> 6;
    const int lane = tid & 63;
    const int r    = lane & 15, g = lane >> 4;
    const int m0   = blockIdx.y * 128;
    const int n0   = blockIdx.x * 128;
    const int wm   = (w >> 1) * 64, wn = (w & 1) * 64;

    f32x4 acc[4][4];
#pragma unroll
    for (int i = 0; i < 4; i++)
#pragma unroll
        for (int j = 0; j < 4; j++) acc[i][j] = (f32x4){0.f, 0.f, 0.f, 0.f};

    // staging: unit u (16B) -> LDS byte u*16 == row-major [row=u>>2][chunk=u&3]
    const int u0 = tid, u1 = 256 + tid;
    const unsigned short* ga0 = A  + (size_t)(m0 + (u0 >> 2)) * K + (u0 & 3) * 8;
    const unsigned short* ga1 = A  + (size_t)(m0 + (u1 >> 2)) * K + (u1 & 3) * 8;
    const unsigned short* gb0 = Bm + (size_t)(n0 + (u0 >> 2)) * K + (u0 & 3) * 8;
    const unsigned short* gb1 = Bm + (size_t)(n0 + (u1 >> 2)) * K + (u1 & 3) * 8;
    unsigned short* la0 = &As[(w * 64) * 8];          // wave-uniform LDS bases
    unsigned short* la1 = &As[(256 + w * 64) * 8];
    unsigned short* lb0 = &Bs[(w * 64) * 8];
    unsigned short* lb1 = &Bs[(256 + w * 64) * 8];

    for (int k0 = 0; k0 < K; k0 += 32) {
        __syncthreads();                               // prev reads done before overwrite
        GLOAD_LDS16(ga0 + k0, la0);
        GLOAD_LDS16(ga1 + k0, la1);
        GLOAD_LDS16(gb0 + k0, lb0);
        GLOAD_LDS16(gb1 + k0, lb1);
        __syncthreads();                               // compiler drains vmcnt(0) at barrier

        bf16x8 a[4], b[4];
#pragma unroll
        for (int mi = 0; mi < 4; mi++) a[mi] = *(const bf16x8*)&As[(wm + mi * 16 + r) * 32 + 8 * g];
#pragma unroll
        for (int ni = 0; ni < 4; ni++) b[ni] = *(const bf16x8*)&Bs[(wn + ni * 16 + r) * 32 + 8 * g];
#pragma unroll
        for (int mi = 0; mi < 4; mi++)
#pragma unroll
            for (int ni = 0; ni < 4; ni++)
                acc[mi][ni] = __builtin_amdgcn_mfma_f32_16x16x32_bf16(a[mi], b[ni], acc[mi][ni], 0, 0, 0);
    }

    // C/D layout: col = lane&15, row = 4*(lane>>4) + reg
#pragma unroll
    for (int mi = 0; mi < 4; mi++) {
        int row = m0 + wm + mi * 16 + 4 * g;
#pragma unroll
        for (int ni = 0; ni < 4; ni++) {
            int col = n0 + wn + ni * 16 + r;
            float bv = bias ? bias[col] : 0.f;
#pragma unroll
            for (int j = 0; j < 4; j++) {
                float v = acc[mi][ni][j] + bv;
                size_t idx = (size_t)(row + j) * N + col;
                if (out_f32) ((float*)Cm)[idx] = v;
                else         ((unsigned short*)Cm)[idx] = f2bf(v);
            }
        }
    }
}

// ---------------- RoPE + split qkv -> Q,K (B,H,T,HD) and V^T (B,H,HD,T) ----------------
__global__ void rope_split(const unsigned short* __restrict__ qkv,
                           const float* __restrict__ fa, const float* __restrict__ fb,
                           unsigned short* __restrict__ Qo, unsigned short* __restrict__ Ko,
                           unsigned short* __restrict__ Vt) {
    const float* fcos = (fa[0] > 0.5f) ? fa : fb;   // cos row at t=0 is all 1.0
    const float* fsin = (fa[0] > 0.5f) ? fb : fa;
    int tid = blockIdx.x * blockDim.x + threadIdx.x;       // total = 4096*1536
    int m  = tid / 1536;
    int d2 = tid - m * 1536;
    int n  = d2 * 2;
    int b  = m >> 11, t = m & 2047;
    u16x2 in = *(const u16x2*)(qkv + (size_t)m * 3072 + n);
    if (n < 2048) {                                        // q or k: apply RoPE
        int nn = n & 1023;
        int h = nn >> 6, d = nn & 63;
        int i = d >> 1;
        float c = fcos[t * 32 + i], s = fsin[t * 32 + i];
        float re = bf2f(in[0]), im = bf2f(in[1]);
        u16x2 o; o[0] = f2bf(re * c - im * s); o[1] = f2bf(re * s + im * c);
        unsigned short* dst = (n < 1024) ? Qo : Ko;
        *(u16x2*)(dst + ((size_t)((b * 16 + h) * 2048 + t)) * 64 + d) = o;
    } else {                                               // v: transpose to (bh, d, t)
        int nn = n - 2048;
        int h = nn >> 6, d = nn & 63;
        size_t base = ((size_t)((b * 16 + h) * 64 + d)) * 2048 + t;
        Vt[base]        = in[0];
        Vt[base + 2048] = in[1];
    }
}

// ---------------- paired-causal flash attention ----------------
// 1 wave owns q-blocks (pr, 127-pr) of one (b,h): constant work per wave, and
// stream A's key range is a prefix of B's -> K/V tile loads shared. KVBLK=64.
// Swapped QK^T (S^T = mfma(K,Q)): D row 4g+j = key slot, col l15 = q-row.
static __device__ __forceinline__ bf16x8 ldv8(const unsigned short* p) {
    union { unsigned w[4]; bf16x8 v; } u;
    const unsigned* q = (const unsigned*)p;
    u.w[0] = q[0]; u.w[1] = q[1]; u.w[2] = q[8]; u.w[3] = q[9];   // 8B at +0, 8B at +16 elts
    return u.v;
}

static __device__ __forceinline__ void softmax64(const f32x4 s[4], int key0, int qrow,
                                                 bool diag, float& m, float& l,
                                                 f32x4 o[4], bf16x8& pf0, bf16x8& pf1, int g) {
    const float SCL = 0.125f * 1.4426950408889634f;   // HD^-0.5 * log2(e)
    float sv[16];
#pragma unroll
    for (int ks = 0; ks < 4; ks++)
#pragma unroll
        for (int j = 0; j < 4; j++) {
            float x = s[ks][j];
            if (diag && (key0 + ks * 16 + 4 * g + j > qrow)) x = NINF;
            sv[ks * 4 + j] = x;
        }
    float t8[8];
#pragma unroll
    for (int i = 0; i < 8; i++) t8[i] = fmaxf(sv[i], sv[i + 8]);
#pragma unroll
    for (int i = 0; i < 4; i++) t8[i] = fmaxf(t8[i], t8[i + 4]);
    float tm = fmaxf(fmaxf(t8[0], t8[1]), fmaxf(t8[2], t8[3]));
    tm = fmaxf(tm, __shfl_xor(tm, 16));
    tm = fmaxf(tm, __shfl_xor(tm, 32));
    float mnew  = fmaxf(m, tm);
    float alpha = exp2f((m - mnew) * SCL);
    float msc   = mnew * SCL;
    float p[16];
#pragma unroll
    for (int i = 0; i < 16; i++) p[i] = exp2f(__builtin_fmaf(sv[i], SCL, -msc));
    float ps0 = ((p[0] + p[1]) + (p[2] + p[3])) + ((p[4] + p[5]) + (p[6] + p[7]));
    float ps1 = ((p[8] + p[9]) + (p[10] + p[11])) + ((p[12] + p[13]) + (p[14] + p[15]));
    l = l * alpha + (ps0 + ps1);
    m = mnew;
#pragma unroll
    for (int ch = 0; ch < 4; ch++) o[ch] *= alpha;
    union { unsigned w[4]; bf16x8 v; } q0, q1;
    asm("v_cvt_pk_bf16_f32 %0, %1, %2" : "=v"(q0.w[0]) : "v"(p[0]),  "v"(p[1]));
    asm("v_cvt_pk_bf16_f32 %0, %1, %2" : "=v"(q0.w[1]) : "v"(p[2]),  "v"(p[3]));
    asm("v_cvt_pk_bf16_f32 %0, %1, %2" : "=v"(q0.w[2]) : "v"(p[4]),  "v"(p[5]));
    asm("v_cvt_pk_bf16_f32 %0, %1, %2" : "=v"(q0.w[3]) : "v"(p[6]),  "v"(p[7]));
    asm("v_cvt_pk_bf16_f32 %0, %1, %2" : "=v"(q1.w[0]) : "v"(p[8]),  "v"(p[9]));
    asm("v_cvt_pk_bf16_f32 %0, %1, %2" : "=v"(q1.w[1]) : "v"(p[10]), "v"(p[11]));
    asm("v_cvt_pk_bf16_f32 %0, %1, %2" : "=v"(q1.w[2]) : "v"(p[12]), "v"(p[13]));
    asm("v_cvt_pk_bf16_f32 %0, %1, %2" : "=v"(q1.w[3]) : "v"(p[14]), "v"(p[15]));
    pf0 = q0.v; pf1 = q1.v;
}

__global__ __launch_bounds__(256) void attn_fwd(const unsigned short* __restrict__ Q,
                                                const unsigned short* __restrict__ Kk,
                                                const unsigned short* __restrict__ Vt,
                                                unsigned short* __restrict__ O) {
    const int w    = threadIdx.x >> 6;
    const int lane = threadIdx.x & 63;
    const int l15  = lane & 15, g = lane >> 4;
    const int gw   = blockIdx.x * 4 + w;      // 0..2047
    const int bh   = gw >> 6;                 // 0..31
    const int pr   = gw & 63;                 // 0..63
    const int b    = bh >> 4, h = bh & 15;
    const int qbA  = pr, qbB = 127 - pr;

    const unsigned short* Qb = Q  + (size_t)bh * T_ * HD_;
    const unsigned short* Kb = Kk + (size_t)bh * T_ * HD_;
    const unsigned short* Vb = Vt + (size_t)bh * HD_ * T_;

    const int qrowA = qbA * 16 + l15, qrowB = qbB * 16 + l15;
    bf16x8 qA0 = *(const bf16x8*)(Qb + (size_t)qrowA * 64 + 8 * g);
    bf16x8 qA1 = *(const bf16x8*)(Qb + (size_t)qrowA * 64 + 32 + 8 * g);
    bf16x8 qB0 = *(const bf16x8*)(Qb + (size_t)qrowB * 64 + 8 * g);
    bf16x8 qB1 = *(const bf16x8*)(Qb + (size_t)qrowB * 64 + 32 + 8 * g);

    f32x4 oA[4], oB[4];
#pragma unroll
    for (int ch = 0; ch < 4; ch++) { oA[ch] = (f32x4){0,0,0,0}; oB[ch] = (f32x4){0,0,0,0}; }
    float mA = NINF, lA = 0.f, mB = NINF, lB = 0.f;
    const int dA = (qbA * 16 + 15) >> 6;      // diagonal (last, masked) tile per stream
    const int dB = (qbB * 16 + 15) >> 6;

    for (int kt = 0; kt <= dB; ++kt) {
        const int key0 = kt * 64;
        const unsigned short* kp = Kb + (size_t)(key0 + l15) * 64 + 8 * g;
        bf16x8 k0a = *(const bf16x8*)(kp);
        bf16x8 k0b = *(const bf16x8*)(kp + 32);
        bf16x8 k1a = *(const bf16x8*)(kp + 1024);
        bf16x8 k1b = *(const bf16x8*)(kp + 1056);
        bf16x8 k2a = *(const bf16x8*)(kp + 2048);
        bf16x8 k2b = *(const bf16x8*)(kp + 2080);
        bf16x8 k3a = *(const bf16x8*)(kp + 3072);
        bf16x8 k3b = *(const bf16x8*)(kp + 3104);

        const bool actA = (kt <= dA);
        f32x4 sB[4], sA[4];
        f32x4 z = (f32x4){0,0,0,0};
        sB[0] = __builtin_amdgcn_mfma_f32_16x16x32_bf16(k0a, qB0, z, 0, 0, 0);
        sB[0] = __builtin_amdgcn_mfma_f32_16x16x32_bf16(k0b, qB1, sB[0], 0, 0, 0);
        sB[1] = __builtin_amdgcn_mfma_f32_16x16x32_bf16(k1a, qB0, z, 0, 0, 0);
        sB[1] = __builtin_amdgcn_mfma_f32_16x16x32_bf16(k1b, qB1, sB[1], 0, 0, 0);
        sB[2] = __builtin_amdgcn_mfma_f32_16x16x32_bf16(k2a, qB0, z, 0, 0, 0);
        sB[2] = __builtin_amdgcn_mfma_f32_16x16x32_bf16(k2b, qB1, sB[2], 0, 0, 0);
        sB[3] = __builtin_amdgcn_mfma_f32_16x16x32_bf16(k3a, qB0, z, 0, 0, 0);
        sB[3] = __builtin_amdgcn_mfma_f32_16x16x32_bf16(k3b, qB1, sB[3], 0, 0, 0);
        if (actA) {
            sA[0] = __builtin_amdgcn_mfma_f32_16x16x32_bf16(k0a, qA0, z, 0, 0, 0);
            sA[0] = __builtin_amdgcn_mfma_f32_16x16x32_bf16(k0b, qA1, sA[0], 0, 0, 0);
            sA[1] = __builtin_amdgcn_mfma_f32_16x16x32_bf16(k1a, qA0, z, 0, 0, 0);
            sA[1] = __builtin_amdgcn_mfma_f32_16x16x32_bf16(k1b, qA1, sA[1], 0, 0, 0);
            sA[2] = __builtin_amdgcn_mfma_f32_16x16x32_bf16(k2a, qA0, z, 0, 0, 0);
            sA[2] = __builtin_amdgcn_mfma_f32_16x16x32_bf16(k2b, qA1, sA[2], 0, 0, 0);
            sA[3] = __builtin_amdgcn_mfma_f32_16x16x32_bf16(k3a, qA0, z, 0, 0, 0);
            sA[3] = __builtin_amdgcn_mfma_f32_16x16x32_bf16(k3b, qA1, sA[3], 0, 0, 0);
        }

        bf16x8 pB0, pB1, pA0, pA1;
        softmax64(sB, key0, qrowB, kt == dB, mB, lB, oB, pB0, pB1, g);
        if (actA) softmax64(sA, key0, qrowA, kt == dA, mA, lA, oA, pA0, pA1, g);

#pragma unroll
        for (int ch = 0; ch < 4; ch++) {
            const unsigned short* vp = Vb + (size_t)(16 * ch + l15) * 2048 + key0 + 4 * g;
            bf16x8 va0 = ldv8(vp);        // k slots: key0+4g+{0..3}, key0+16+4g+{0..3}
            bf16x8 va1 = ldv8(vp + 32);   // +32, +48
            oB[ch] = __builtin_amdgcn_mfma_f32_16x16x32_bf16(va0, pB0, oB[ch], 0, 0, 0);
            oB[ch] = __builtin_amdgcn_mfma_f32_16x16x32_bf16(va1, pB1, oB[ch], 0, 0, 0);
            if (actA) {
                oA[ch] = __builtin_amdgcn_mfma_f32_16x16x32_bf16(va0, pA0, oA[ch], 0, 0, 0);
                oA[ch] = __builtin_amdgcn_mfma_f32_16x16x32_bf16(va1, pA1, oA[ch], 0, 0, 0);
            }
        }
    }

    lA += __shfl_xor(lA, 16); lA += __shfl_xor(lA, 32);
    lB += __shfl_xor(lB, 16); lB += __shfl_xor(lB, 32);
    float invA = 1.f / lA, invB = 1.f / lB;

    size_t obA = (((size_t)b * T_ + qrowA) * H_ + h) * HD_;
    size_t obB = (((size_t)b * T_ + qrowB) * H_ + h) * HD_;
#pragma unroll
    for (int ch = 0; ch < 4; ch++) {
        int d0 = 16 * ch + 4 * g;
        u16x4 va, vb;
#pragma unroll
        for (int j = 0; j < 4; j++) { va[j] = f2bf(oA[ch][j] * invA); vb[j] = f2bf(oB[ch][j] * invB); }
        *(u16x4*)(O + obA + d0) = va;
        *(u16x4*)(O + obB + d0) = vb;
    }
}

extern "C" void kernel_launch(void* const* d_in, const int* in_sizes, int n_in,
                              void* d_out, int out_size, void* d_ws, size_t ws_size,
                              hipStream_t stream) {
    (void)out_size;
    const float *x = nullptr, *wqkv = nullptr, *wproj = nullptr, *bproj = nullptr;
    const float *fa = nullptr, *fb = nullptr;
    for (int i = 0; i < n_in; i++) {
        switch (in_sizes[i]) {
            case 4194304: x     = (const float*)d_in[i]; break;
            case 3145728: wqkv  = (const float*)d_in[i]; break;
            case 1048576: wproj = (const float*)d_in[i]; break;
            case 1024:    bproj = (const float*)d_in[i]; break;
            case 65536:   if (!fa) fa = (const float*)d_in[i]; else fb = (const float*)d_in[i]; break;
            default: break;
        }
    }
    if (!x || !wqkv || !wproj || !bproj || !fa || !fb) return;
    if (ws_size < (size_t)48 * 1024 * 1024) return;

    char* ws = (char*)d_ws;
    const size_t MB = 1024 * 1024;
    unsigned short* qkv    = (unsigned short*)(ws);            // [0,24M)
    unsigned short* oat    = (unsigned short*)(ws);            // [0,8M)   (after rope)
    unsigned short* wprojb = (unsigned short*)(ws + 8  * MB);  // [8,10M)  (after rope)
    unsigned short* xb     = (unsigned short*)(ws + 24 * MB);  // [24,32M)
    unsigned short* wqkvb  = (unsigned short*)(ws + 32 * MB);  // [32,38M)
    unsigned short* qro    = (unsigned short*)(ws + 24 * MB);  // [24,32M)
    unsigned short* kro    = (unsigned short*)(ws + 32 * MB);  // [32,40M)
    unsigned short* vt     = (unsigned short*)(ws + 40 * MB);  // [40,48M)

    convert_f32_bf16<<<4096, 256, 0, stream>>>(x,    xb,    4194304 / 4);
    convert_f32_bf16<<<3072, 256, 0, stream>>>(wqkv, wqkvb, 3145728 / 4);

    gemm_nt<<<dim3(3072 / 128, 4096 / 128), 256, 0, stream>>>(xb, wqkvb, qkv, nullptr,
                                                              4096, 3072, 1024, 0);

    rope_split<<<(4096 * 1536) / 256, 256, 0, stream>>>(qkv, fa, fb, qro, kro, vt);

    convert_f32_bf16<<<1024, 256, 0, stream>>>(wproj, wprojb, 1048576 / 4);

    attn_fwd<<<512, 256, 0, stream>>>(qro, kro, vt, oat);

    gemm_nt<<<dim3(1024 / 128, 4096 / 128), 256, 0, stream>>>(oat, wprojb, d_out, bproj,
                                                              4096, 1024, 1024, 1);
}